// Round 9
// baseline (152.170 us; speedup 1.0000x reference)
//
#include <hip/hip_runtime.h>
#include <math.h>

#define NQ   512
#define NKV  1280
#define CDIM 128
#define L2E  1.4426950408889634f

// workspace layout (float offsets)
#define OFF_WDSUM 0        // 3
#define OFF_SUMS  16       // 1024: [br][512] row sums (zeroed by prep)
#define OFF_QSA   1056     // 65536 [n=512][c=128]
#define OFF_QDA   66592    // 65536 (prescaled by log2e)
#define OFF_KSAT  132128   // 163840 [c=128][k=1280]
#define OFF_VSA   295968   // 163840 [k=1280][c=128]
#define OFF_KDAT  459808   // 163840 (prescaled by log2e)
#define OFF_VDA   623648   // 163840
#define OFF_OUT   787488   // 131072: [br][512][128] unnormalized AV (zeroed)
// total 918560 floats = 3.67 MB

// ---------------------------------------------------------------- prep
// bx<320: kv proj (4 keys); bx in [320,448): q proj (4 rows);
// bx==448: wdsum + zero sums; bx in [449,577): zero OUT.
__global__ __launch_bounds__(256) void prep_kernel(
    const float* __restrict__ erp, const float* __restrict__ ico,
    const float* __restrict__ wq_sa, const float* __restrict__ wq_da,
    const float* __restrict__ wkv_sa, const float* __restrict__ wkv_da,
    const float* __restrict__ wdelta, float* __restrict__ ws)
{
  int bx = blockIdx.x, t = threadIdx.x;
  if (bx < 320) {
    __shared__ float x4[4 * CDIM];          // [j*4 + ky]
    int k0 = bx * 4;
    for (int i = t; i < 512; i += 256) {
      int ky = i >> 7, j = i & 127;
      x4[j * 4 + ky] = ico[(k0 + ky) * CDIM + j];
    }
    __syncthreads();
    const float4* wsa4 = (const float4*)(wkv_sa + t * CDIM);
    const float4* wda4 = (const float4*)(wkv_da + t * CDIM);
    float as0=0,as1=0,as2=0,as3=0, ad0=0,ad1=0,ad2=0,ad3=0;
    #pragma unroll 4
    for (int j4 = 0; j4 < 32; ++j4) {
      float4 wsv = wsa4[j4];
      float4 wdv = wda4[j4];
      float4 x0 = *(const float4*)&x4[(j4 * 4 + 0) * 4];
      float4 x1 = *(const float4*)&x4[(j4 * 4 + 1) * 4];
      float4 x2 = *(const float4*)&x4[(j4 * 4 + 2) * 4];
      float4 x3 = *(const float4*)&x4[(j4 * 4 + 3) * 4];
      as0 = fmaf(wsv.x, x0.x, as0); as1 = fmaf(wsv.x, x0.y, as1);
      as2 = fmaf(wsv.x, x0.z, as2); as3 = fmaf(wsv.x, x0.w, as3);
      ad0 = fmaf(wdv.x, x0.x, ad0); ad1 = fmaf(wdv.x, x0.y, ad1);
      ad2 = fmaf(wdv.x, x0.z, ad2); ad3 = fmaf(wdv.x, x0.w, ad3);
      as0 = fmaf(wsv.y, x1.x, as0); as1 = fmaf(wsv.y, x1.y, as1);
      as2 = fmaf(wsv.y, x1.z, as2); as3 = fmaf(wsv.y, x1.w, as3);
      ad0 = fmaf(wdv.y, x1.x, ad0); ad1 = fmaf(wdv.y, x1.y, ad1);
      ad2 = fmaf(wdv.y, x1.z, ad2); ad3 = fmaf(wdv.y, x1.w, ad3);
      as0 = fmaf(wsv.z, x2.x, as0); as1 = fmaf(wsv.z, x2.y, as1);
      as2 = fmaf(wsv.z, x2.z, as2); as3 = fmaf(wsv.z, x2.w, as3);
      ad0 = fmaf(wdv.z, x2.x, ad0); ad1 = fmaf(wdv.z, x2.y, ad1);
      ad2 = fmaf(wdv.z, x2.z, ad2); ad3 = fmaf(wdv.z, x2.w, ad3);
      as0 = fmaf(wsv.w, x3.x, as0); as1 = fmaf(wsv.w, x3.y, as1);
      as2 = fmaf(wsv.w, x3.z, as2); as3 = fmaf(wsv.w, x3.w, as3);
      ad0 = fmaf(wdv.w, x3.x, ad0); ad1 = fmaf(wdv.w, x3.y, ad1);
      ad2 = fmaf(wdv.w, x3.z, ad2); ad3 = fmaf(wdv.w, x3.w, ad3);
    }
    if (t < 128) {   // k features -> transposed [c][k]; K_da prescaled
      *(float4*)(ws + OFF_KSAT + t * NKV + k0) = make_float4(as0, as1, as2, as3);
      *(float4*)(ws + OFF_KDAT + t * NKV + k0) =
          make_float4(ad0 * L2E, ad1 * L2E, ad2 * L2E, ad3 * L2E);
    } else {         // v features -> [k][c]
      int c = t - 128;
      ws[OFF_VSA + (k0 + 0) * CDIM + c] = as0;
      ws[OFF_VSA + (k0 + 1) * CDIM + c] = as1;
      ws[OFF_VSA + (k0 + 2) * CDIM + c] = as2;
      ws[OFF_VSA + (k0 + 3) * CDIM + c] = as3;
      ws[OFF_VDA + (k0 + 0) * CDIM + c] = ad0;
      ws[OFF_VDA + (k0 + 1) * CDIM + c] = ad1;
      ws[OFF_VDA + (k0 + 2) * CDIM + c] = ad2;
      ws[OFF_VDA + (k0 + 3) * CDIM + c] = ad3;
    }
  } else if (bx < 448) {
    // q projection, 4 rows; t<128 -> q_sa out c=t, t>=128 -> q_da (prescaled)
    __shared__ float q4[4 * CDIM];          // [j*4 + r]
    int n0 = (bx - 320) * 4;
    for (int i = t; i < 512; i += 256)
      q4[i] = erp[(i >> 2) * NQ + n0 + (i & 3)];
    __syncthreads();
    const float* w = (t < 128) ? wq_sa : wq_da;
    int c = t & 127;
    const float4* w4 = (const float4*)(w + c * CDIM);
    float a0 = 0.f, a1 = 0.f, a2 = 0.f, a3 = 0.f;
    #pragma unroll 8
    for (int j4 = 0; j4 < 32; ++j4) {
      float4 wv = w4[j4];
      float4 q0 = *(const float4*)&q4[(j4 * 4 + 0) * 4];
      float4 q1 = *(const float4*)&q4[(j4 * 4 + 1) * 4];
      float4 q2 = *(const float4*)&q4[(j4 * 4 + 2) * 4];
      float4 q3 = *(const float4*)&q4[(j4 * 4 + 3) * 4];
      a0 = fmaf(wv.x, q0.x, a0); a1 = fmaf(wv.x, q0.y, a1);
      a2 = fmaf(wv.x, q0.z, a2); a3 = fmaf(wv.x, q0.w, a3);
      a0 = fmaf(wv.y, q1.x, a0); a1 = fmaf(wv.y, q1.y, a1);
      a2 = fmaf(wv.y, q1.z, a2); a3 = fmaf(wv.y, q1.w, a3);
      a0 = fmaf(wv.z, q2.x, a0); a1 = fmaf(wv.z, q2.y, a1);
      a2 = fmaf(wv.z, q2.z, a2); a3 = fmaf(wv.z, q2.w, a3);
      a0 = fmaf(wv.w, q3.x, a0); a1 = fmaf(wv.w, q3.y, a1);
      a2 = fmaf(wv.w, q3.z, a2); a3 = fmaf(wv.w, q3.w, a3);
    }
    float sc = (t < 128) ? 1.0f : L2E;
    float* o = ws + ((t < 128) ? OFF_QSA : OFF_QDA);
    o[(n0 + 0) * CDIM + c] = a0 * sc;
    o[(n0 + 1) * CDIM + c] = a1 * sc;
    o[(n0 + 2) * CDIM + c] = a2 * sc;
    o[(n0 + 3) * CDIM + c] = a3 * sc;
  } else if (bx == 448) {
    *(float4*)(ws + OFF_SUMS + t * 4) = make_float4(0.f, 0.f, 0.f, 0.f);
    if (t < 3) {   // Wdelta.sum(0)
      float s = 0.f;
      for (int i = 0; i < 128; ++i) s += wdelta[i * 3 + t];
      ws[OFF_WDSUM + t] = s;
    }
  } else {
    int base = OFF_OUT + (bx - 449) * 1024 + t * 4;
    *(float4*)(ws + base) = make_float4(0.f, 0.f, 0.f, 0.f);
  }
}

// ---------------------------------------------------------------- attn
// 1280 blocks, 1D, da first (b<640). Each block: 8 q-rows, 128-k slice.
// Score: each k handled by 2 threads (64 j's each), partials merged in LDS.
// da uses exp2 on prescaled q/K (identical values to expf). No-max softmax.
// e = exp(logit) -> atomicAdd row sums -> AV -> atomicAdd OUT.
__global__ __launch_bounds__(256) void attn_kernel(
    const float* __restrict__ coord, float* __restrict__ ws)
{
  __shared__ __align__(16) float qjf[8 * CDIM];  // [j*8 + r]
  __shared__ __align__(16) float psc[2][8][128]; // [jh][r][k]
  __shared__ __align__(16) float posk[8][128];   // pos_aff (da only)
  __shared__ __align__(16) float se[8][128];     // exp(logit)
  __shared__ float red[2][8];
  __shared__ float qcr[8][3];
  __shared__ float wdl[3];
  int b = blockIdx.x, t = threadIdx.x;
  int br = (b < 640) ? 1 : 0;         // da blocks dispatched first
  int bb = br ? b : b - 640;
  int g = bb / 10, z = bb - g * 10;
  int n0 = g * 8, k0 = z * 128;

  const float* qsrc = ws + (br ? OFF_QDA : OFF_QSA);
  for (int i = t; i < 1024; i += 256) {
    int r = i & 7, j = i >> 3;
    qjf[j * 8 + r] = qsrc[(n0 + r) * CDIM + j];
  }
  if (br) {
    if (t < 8) {
      int n = n0 + t;
      float x = (float)(n & 31), y = (float)(n >> 5);
      float u  = (x - 16.5f) * 0.19634954084936207f;  // pi/16
      float vv = (y -  8.5f) * 0.19634954084936207f;
      float cv = cosf(vv);
      qcr[t][0] = cv * sinf(u) * L2E;
      qcr[t][1] = sinf(vv) * L2E;
      qcr[t][2] = cv * cosf(u) * L2E;
    }
    if (t >= 64 && t < 67) wdl[t - 64] = ws[OFF_WDSUM + t - 64];
  }
  __syncthreads();

  int kl = t & 127, jh = t >> 7;
  int k = k0 + kl;
  {  // partial scores over this thread's 64-j half, 8 rows
    const float* kp = ws + (br ? OFF_KDAT : OFF_KSAT) + k + jh * 64 * NKV;
    const float4* qj = (const float4*)&qjf[jh * 64 * 8];
    float a0=0,a1=0,a2=0,a3=0,a4=0,a5=0,a6=0,a7=0;
    if (br) {
      #pragma unroll 4
      for (int j = 0; j < 64; ++j) {
        float kv = kp[j * NKV];
        float4 qa = qj[j * 2], qb = qj[j * 2 + 1];
        a0 += exp2f(-fabsf(qa.x - kv)); a1 += exp2f(-fabsf(qa.y - kv));
        a2 += exp2f(-fabsf(qa.z - kv)); a3 += exp2f(-fabsf(qa.w - kv));
        a4 += exp2f(-fabsf(qb.x - kv)); a5 += exp2f(-fabsf(qb.y - kv));
        a6 += exp2f(-fabsf(qb.z - kv)); a7 += exp2f(-fabsf(qb.w - kv));
      }
    } else {
      #pragma unroll 4
      for (int j = 0; j < 64; ++j) {
        float kv = kp[j * NKV];
        float4 qa = qj[j * 2], qb = qj[j * 2 + 1];
        a0 = fmaf(qa.x, kv, a0); a1 = fmaf(qa.y, kv, a1);
        a2 = fmaf(qa.z, kv, a2); a3 = fmaf(qa.w, kv, a3);
        a4 = fmaf(qb.x, kv, a4); a5 = fmaf(qb.y, kv, a5);
        a6 = fmaf(qb.z, kv, a6); a7 = fmaf(qb.w, kv, a7);
      }
    }
    psc[jh][0][kl] = a0; psc[jh][1][kl] = a1;
    psc[jh][2][kl] = a2; psc[jh][3][kl] = a3;
    psc[jh][4][kl] = a4; psc[jh][5][kl] = a5;
    psc[jh][6][kl] = a6; psc[jh][7][kl] = a7;
    if (br && jh == 1) {   // pos_aff for k, all 8 rows (prescaled coords)
      float c0 = coord[k * 3] * L2E;
      float c1 = coord[k * 3 + 1] * L2E;
      float c2 = coord[k * 3 + 2] * L2E;
      float w0 = wdl[0], w1 = wdl[1], w2 = wdl[2];
      #pragma unroll
      for (int r = 0; r < 8; ++r)
        posk[r][kl] = w0 * exp2f(-fabsf(qcr[r][0] - c0))
                    + w1 * exp2f(-fabsf(qcr[r][1] - c1))
                    + w2 * exp2f(-fabsf(qcr[r][2] - c2));
    }
  }
  __syncthreads();

  if (t < 128) {  // merge partials, exp2, reduce sums (waves 0-1)
    const float csa = 0.088388347648318447f * L2E;  // 128^-0.5 * log2e
    const float cda = 0.0078125f * L2E;             // (1/C) * log2e
    float s[8];
    #pragma unroll
    for (int r = 0; r < 8; ++r) {
      float tot = psc[0][r][t] + psc[1][r][t];
      float l = br ? (tot + posk[r][t]) * cda : tot * csa;
      float e = exp2f(l);
      se[r][t] = e;
      s[r] = e;
    }
    #pragma unroll
    for (int o = 32; o > 0; o >>= 1) {
      #pragma unroll
      for (int r = 0; r < 8; ++r) s[r] += __shfl_down(s[r], o, 64);
    }
    if ((t & 63) == 0) {
      int w = t >> 6;
      #pragma unroll
      for (int r = 0; r < 8; ++r) red[w][r] = s[r];
    }
  }
  __syncthreads();   // covers se[] and red[]
  if (t < 8)
    atomicAdd(ws + OFF_SUMS + br * 512 + n0 + t, red[0][t] + red[1][t]);

  // AV: thread (c=t&127, h=t>>7) -> rows h, h+2, h+4, h+6 over all 128 ks
  int c = t & 127, h = t >> 7;
  const float* vp = ws + (br ? OFF_VDA : OFF_VSA) + k0 * CDIM + c;
  float acc0 = 0.f, acc1 = 0.f, acc2 = 0.f, acc3 = 0.f;
  #pragma unroll 4
  for (int ko = 0; ko < 128; ko += 4) {
    float4 p0 = *(const float4*)&se[h][ko];
    float4 p1 = *(const float4*)&se[h + 2][ko];
    float4 p2 = *(const float4*)&se[h + 4][ko];
    float4 p3 = *(const float4*)&se[h + 6][ko];
    float v0 = vp[(ko + 0) * CDIM];
    float v1 = vp[(ko + 1) * CDIM];
    float v2 = vp[(ko + 2) * CDIM];
    float v3 = vp[(ko + 3) * CDIM];
    acc0 = fmaf(p0.x, v0, acc0); acc1 = fmaf(p1.x, v0, acc1);
    acc2 = fmaf(p2.x, v0, acc2); acc3 = fmaf(p3.x, v0, acc3);
    acc0 = fmaf(p0.y, v1, acc0); acc1 = fmaf(p1.y, v1, acc1);
    acc2 = fmaf(p2.y, v1, acc2); acc3 = fmaf(p3.y, v1, acc3);
    acc0 = fmaf(p0.z, v2, acc0); acc1 = fmaf(p1.z, v2, acc1);
    acc2 = fmaf(p2.z, v2, acc2); acc3 = fmaf(p3.z, v2, acc3);
    acc0 = fmaf(p0.w, v3, acc0); acc1 = fmaf(p1.w, v3, acc1);
    acc2 = fmaf(p2.w, v3, acc2); acc3 = fmaf(p3.w, v3, acc3);
  }
  float* op = ws + OFF_OUT + br * (NQ * CDIM);
  atomicAdd(op + (n0 + h) * CDIM + c,     acc0);
  atomicAdd(op + (n0 + h + 2) * CDIM + c, acc1);
  atomicAdd(op + (n0 + h + 4) * CDIM + c, acc2);
  atomicAdd(op + (n0 + h + 6) * CDIM + c, acc3);
}

// ---------------------------------------------------------------- finalize
// one block (256 thr) per 4 query rows: normalize (divide by sums) with the
// reference's transpose-reshape on sa, project both, gate, fuse, NCHW store.
__global__ __launch_bounds__(256) void finalize_kernel(
    const float* __restrict__ psa, const float* __restrict__ bsa,
    const float* __restrict__ pda, const float* __restrict__ bda,
    const float* __restrict__ gsa, const float* __restrict__ gda,
    float* __restrict__ out, float* __restrict__ ws)
{
  __shared__ float sain[4][CDIM];
  __shared__ float dain[4][CDIM];
  __shared__ float cat[4][2 * CDIM];
  __shared__ float gl[4][2][CDIM];
  int i0 = blockIdx.x * 4, t = threadIdx.x;
  int h = t >> 7, c = t & 127;
  #pragma unroll
  for (int rr = 0; rr < 4; ++rr) {
    int i = i0 + rr;
    if (h == 0) {
      // sa_in[i][c] = out_sa[(i%4)*128 + c][i/4] / sum_sa[(i%4)*128 + c]
      int row = (i & 3) * 128 + c;
      float s = ws[OFF_SUMS + row];
      sain[rr][c] = ws[OFF_OUT + row * CDIM + (i >> 2)] / s;
    } else {
      float s = ws[OFF_SUMS + 512 + i];
      dain[rr][c] = ws[OFF_OUT + NQ * CDIM + i * CDIM + c] / s;
    }
  }
  __syncthreads();
  {
    const float4* w4 = (const float4*)((h ? pda : psa) + c * CDIM);
    float a0 = 0, a1 = 0, a2 = 0, a3 = 0;
    #pragma unroll 4
    for (int j4 = 0; j4 < 32; ++j4) {
      float4 wv = w4[j4];
      const float (*inp)[CDIM] = h ? dain : sain;
      float4 x0 = *(const float4*)&inp[0][j4 * 4];
      float4 x1 = *(const float4*)&inp[1][j4 * 4];
      float4 x2 = *(const float4*)&inp[2][j4 * 4];
      float4 x3 = *(const float4*)&inp[3][j4 * 4];
      a0 = fmaf(wv.x, x0.x, a0); a0 = fmaf(wv.y, x0.y, a0);
      a0 = fmaf(wv.z, x0.z, a0); a0 = fmaf(wv.w, x0.w, a0);
      a1 = fmaf(wv.x, x1.x, a1); a1 = fmaf(wv.y, x1.y, a1);
      a1 = fmaf(wv.z, x1.z, a1); a1 = fmaf(wv.w, x1.w, a1);
      a2 = fmaf(wv.x, x2.x, a2); a2 = fmaf(wv.y, x2.y, a2);
      a2 = fmaf(wv.z, x2.z, a2); a2 = fmaf(wv.w, x2.w, a2);
      a3 = fmaf(wv.x, x3.x, a3); a3 = fmaf(wv.y, x3.y, a3);
      a3 = fmaf(wv.z, x3.z, a3); a3 = fmaf(wv.w, x3.w, a3);
    }
    float bias = h ? bda[c] : bsa[c];
    cat[0][h * CDIM + c] = bias + a0;
    cat[1][h * CDIM + c] = bias + a1;
    cat[2][h * CDIM + c] = bias + a2;
    cat[3][h * CDIM + c] = bias + a3;
  }
  __syncthreads();
  {
    const float4* g4 = (const float4*)((h ? gda : gsa) + c * 2 * CDIM);
    float a0 = 0, a1 = 0, a2 = 0, a3 = 0;
    #pragma unroll 4
    for (int j4 = 0; j4 < 64; ++j4) {
      float4 gv = g4[j4];
      float4 c0 = *(const float4*)&cat[0][j4 * 4];
      float4 c1 = *(const float4*)&cat[1][j4 * 4];
      float4 c2 = *(const float4*)&cat[2][j4 * 4];
      float4 c3 = *(const float4*)&cat[3][j4 * 4];
      a0 = fmaf(gv.x, c0.x, a0); a0 = fmaf(gv.y, c0.y, a0);
      a0 = fmaf(gv.z, c0.z, a0); a0 = fmaf(gv.w, c0.w, a0);
      a1 = fmaf(gv.x, c1.x, a1); a1 = fmaf(gv.y, c1.y, a1);
      a1 = fmaf(gv.z, c1.z, a1); a1 = fmaf(gv.w, c1.w, a1);
      a2 = fmaf(gv.x, c2.x, a2); a2 = fmaf(gv.y, c2.y, a2);
      a2 = fmaf(gv.z, c2.z, a2); a2 = fmaf(gv.w, c2.w, a2);
      a3 = fmaf(gv.x, c3.x, a3); a3 = fmaf(gv.y, c3.y, a3);
      a3 = fmaf(gv.z, c3.z, a3); a3 = fmaf(gv.w, c3.w, a3);
    }
    gl[0][h][c] = 1.0f / (1.0f + __expf(-a0));
    gl[1][h][c] = 1.0f / (1.0f + __expf(-a1));
    gl[2][h][c] = 1.0f / (1.0f + __expf(-a2));
    gl[3][h][c] = 1.0f / (1.0f + __expf(-a3));
  }
  __syncthreads();
  #pragma unroll
  for (int u = 0; u < 2; ++u) {   // each thread stores 2 of the 4 rows
    int rr = h * 2 + u;
    int i = i0 + rr;
    out[c * NQ + i] = gl[rr][0][c] * cat[rr][c] + gl[rr][1][c] * cat[rr][CDIM + c];
  }
}

// ---------------------------------------------------------------- launch
extern "C" void kernel_launch(void* const* d_in, const int* in_sizes, int n_in,
                              void* d_out, int out_size, void* d_ws, size_t ws_size,
                              hipStream_t stream)
{
  (void)in_sizes; (void)n_in; (void)out_size; (void)ws_size;
  const float* erp       = (const float*)d_in[0];
  const float* ico       = (const float*)d_in[1];
  const float* coord     = (const float*)d_in[2];
  const float* wq_sa     = (const float*)d_in[3];
  const float* wkv_sa    = (const float*)d_in[4];
  const float* proj_sa_w = (const float*)d_in[5];
  const float* proj_sa_b = (const float*)d_in[6];
  const float* wq_da     = (const float*)d_in[7];
  const float* wkv_da    = (const float*)d_in[8];
  const float* wdelta    = (const float*)d_in[9];
  const float* proj_da_w = (const float*)d_in[10];
  const float* proj_da_b = (const float*)d_in[11];
  const float* gate_sa   = (const float*)d_in[12];
  const float* gate_da   = (const float*)d_in[13];
  float* out = (float*)d_out;
  float* ws  = (float*)d_ws;

  hipLaunchKernelGGL(prep_kernel, dim3(577), dim3(256), 0, stream,
                     erp, ico, wq_sa, wq_da, wkv_sa, wkv_da, wdelta, ws);
  hipLaunchKernelGGL(attn_kernel, dim3(1280), dim3(256), 0, stream,
                     coord, ws);
  hipLaunchKernelGGL(finalize_kernel, dim3(128), dim3(256), 0, stream,
                     proj_sa_w, proj_sa_b, proj_da_w, proj_da_b,
                     gate_sa, gate_da, out, ws);
}

// Round 10
// 147.490 us; speedup vs baseline: 1.0317x; 1.0317x over previous
//
#include <hip/hip_runtime.h>
#include <math.h>

#define NQ   512
#define NKV  1280
#define CDIM 128
#define L2E  1.4426950408889634f

// workspace layout (float offsets)
#define OFF_WDSUM 0        // 3
#define OFF_SUMS  16       // 1024: [br][512] row sums (zeroed by prep)
#define OFF_QSA   1056     // 65536 [n=512][c=128]
#define OFF_QDA   66592    // 65536 (prescaled by log2e)
#define OFF_KSAT  132128   // 163840 [c=128][k=1280]
#define OFF_VSA   295968   // 163840 [k=1280][c=128]
#define OFF_KDAT  459808   // 163840 (prescaled by log2e)
#define OFF_VDA   623648   // 163840
#define OFF_OUT   787488   // 131072: [br][512][128] unnormalized AV (zeroed)
// total 918560 floats = 3.67 MB

// ---------------------------------------------------------------- prep
// bx<320: kv proj (4 keys); bx in [320,448): q proj (4 rows);
// bx==448: wdsum + zero sums; bx in [449,577): zero OUT.
__global__ __launch_bounds__(256) void prep_kernel(
    const float* __restrict__ erp, const float* __restrict__ ico,
    const float* __restrict__ wq_sa, const float* __restrict__ wq_da,
    const float* __restrict__ wkv_sa, const float* __restrict__ wkv_da,
    const float* __restrict__ wdelta, float* __restrict__ ws)
{
  int bx = blockIdx.x, t = threadIdx.x;
  if (bx < 320) {
    __shared__ float x4[4 * CDIM];          // [j*4 + ky]
    int k0 = bx * 4;
    for (int i = t; i < 512; i += 256) {
      int ky = i >> 7, j = i & 127;
      x4[j * 4 + ky] = ico[(k0 + ky) * CDIM + j];
    }
    __syncthreads();
    const float4* wsa4 = (const float4*)(wkv_sa + t * CDIM);
    const float4* wda4 = (const float4*)(wkv_da + t * CDIM);
    float as0=0,as1=0,as2=0,as3=0, ad0=0,ad1=0,ad2=0,ad3=0;
    #pragma unroll 4
    for (int j4 = 0; j4 < 32; ++j4) {
      float4 wsv = wsa4[j4];
      float4 wdv = wda4[j4];
      float4 x0 = *(const float4*)&x4[(j4 * 4 + 0) * 4];
      float4 x1 = *(const float4*)&x4[(j4 * 4 + 1) * 4];
      float4 x2 = *(const float4*)&x4[(j4 * 4 + 2) * 4];
      float4 x3 = *(const float4*)&x4[(j4 * 4 + 3) * 4];
      as0 = fmaf(wsv.x, x0.x, as0); as1 = fmaf(wsv.x, x0.y, as1);
      as2 = fmaf(wsv.x, x0.z, as2); as3 = fmaf(wsv.x, x0.w, as3);
      ad0 = fmaf(wdv.x, x0.x, ad0); ad1 = fmaf(wdv.x, x0.y, ad1);
      ad2 = fmaf(wdv.x, x0.z, ad2); ad3 = fmaf(wdv.x, x0.w, ad3);
      as0 = fmaf(wsv.y, x1.x, as0); as1 = fmaf(wsv.y, x1.y, as1);
      as2 = fmaf(wsv.y, x1.z, as2); as3 = fmaf(wsv.y, x1.w, as3);
      ad0 = fmaf(wdv.y, x1.x, ad0); ad1 = fmaf(wdv.y, x1.y, ad1);
      ad2 = fmaf(wdv.y, x1.z, ad2); ad3 = fmaf(wdv.y, x1.w, ad3);
      as0 = fmaf(wsv.z, x2.x, as0); as1 = fmaf(wsv.z, x2.y, as1);
      as2 = fmaf(wsv.z, x2.z, as2); as3 = fmaf(wsv.z, x2.w, as3);
      ad0 = fmaf(wdv.z, x2.x, ad0); ad1 = fmaf(wdv.z, x2.y, ad1);
      ad2 = fmaf(wdv.z, x2.z, ad2); ad3 = fmaf(wdv.z, x2.w, ad3);
      as0 = fmaf(wsv.w, x3.x, as0); as1 = fmaf(wsv.w, x3.y, as1);
      as2 = fmaf(wsv.w, x3.z, as2); as3 = fmaf(wsv.w, x3.w, as3);
      ad0 = fmaf(wdv.w, x3.x, ad0); ad1 = fmaf(wdv.w, x3.y, ad1);
      ad2 = fmaf(wdv.w, x3.z, ad2); ad3 = fmaf(wdv.w, x3.w, ad3);
    }
    if (t < 128) {   // k features -> transposed [c][k]; K_da prescaled
      *(float4*)(ws + OFF_KSAT + t * NKV + k0) = make_float4(as0, as1, as2, as3);
      *(float4*)(ws + OFF_KDAT + t * NKV + k0) =
          make_float4(ad0 * L2E, ad1 * L2E, ad2 * L2E, ad3 * L2E);
    } else {         // v features -> [k][c]
      int c = t - 128;
      ws[OFF_VSA + (k0 + 0) * CDIM + c] = as0;
      ws[OFF_VSA + (k0 + 1) * CDIM + c] = as1;
      ws[OFF_VSA + (k0 + 2) * CDIM + c] = as2;
      ws[OFF_VSA + (k0 + 3) * CDIM + c] = as3;
      ws[OFF_VDA + (k0 + 0) * CDIM + c] = ad0;
      ws[OFF_VDA + (k0 + 1) * CDIM + c] = ad1;
      ws[OFF_VDA + (k0 + 2) * CDIM + c] = ad2;
      ws[OFF_VDA + (k0 + 3) * CDIM + c] = ad3;
    }
  } else if (bx < 448) {
    // q projection, 4 rows; t<128 -> q_sa out c=t, t>=128 -> q_da (prescaled)
    __shared__ float q4[4 * CDIM];          // [j*4 + r]
    int n0 = (bx - 320) * 4;
    for (int i = t; i < 512; i += 256)
      q4[i] = erp[(i >> 2) * NQ + n0 + (i & 3)];
    __syncthreads();
    const float* w = (t < 128) ? wq_sa : wq_da;
    int c = t & 127;
    const float4* w4 = (const float4*)(w + c * CDIM);
    float a0 = 0.f, a1 = 0.f, a2 = 0.f, a3 = 0.f;
    #pragma unroll 8
    for (int j4 = 0; j4 < 32; ++j4) {
      float4 wv = w4[j4];
      float4 q0 = *(const float4*)&q4[(j4 * 4 + 0) * 4];
      float4 q1 = *(const float4*)&q4[(j4 * 4 + 1) * 4];
      float4 q2 = *(const float4*)&q4[(j4 * 4 + 2) * 4];
      float4 q3 = *(const float4*)&q4[(j4 * 4 + 3) * 4];
      a0 = fmaf(wv.x, q0.x, a0); a1 = fmaf(wv.x, q0.y, a1);
      a2 = fmaf(wv.x, q0.z, a2); a3 = fmaf(wv.x, q0.w, a3);
      a0 = fmaf(wv.y, q1.x, a0); a1 = fmaf(wv.y, q1.y, a1);
      a2 = fmaf(wv.y, q1.z, a2); a3 = fmaf(wv.y, q1.w, a3);
      a0 = fmaf(wv.z, q2.x, a0); a1 = fmaf(wv.z, q2.y, a1);
      a2 = fmaf(wv.z, q2.z, a2); a3 = fmaf(wv.z, q2.w, a3);
      a0 = fmaf(wv.w, q3.x, a0); a1 = fmaf(wv.w, q3.y, a1);
      a2 = fmaf(wv.w, q3.z, a2); a3 = fmaf(wv.w, q3.w, a3);
    }
    float sc = (t < 128) ? 1.0f : L2E;
    float* o = ws + ((t < 128) ? OFF_QSA : OFF_QDA);
    o[(n0 + 0) * CDIM + c] = a0 * sc;
    o[(n0 + 1) * CDIM + c] = a1 * sc;
    o[(n0 + 2) * CDIM + c] = a2 * sc;
    o[(n0 + 3) * CDIM + c] = a3 * sc;
  } else if (bx == 448) {
    *(float4*)(ws + OFF_SUMS + t * 4) = make_float4(0.f, 0.f, 0.f, 0.f);
    if (t < 3) {   // Wdelta.sum(0)
      float s = 0.f;
      for (int i = 0; i < 128; ++i) s += wdelta[i * 3 + t];
      ws[OFF_WDSUM + t] = s;
    }
  } else {
    int base = OFF_OUT + (bx - 449) * 1024 + t * 4;
    *(float4*)(ws + base) = make_float4(0.f, 0.f, 0.f, 0.f);
  }
}

// ---------------------------------------------------------------- attn
// 2560 blocks, 1D, da first (b<1280). Each block: 4 q-rows, 128-k slice.
// (R8-proven shape.) Score: each k handled by 2 threads (64 j's each),
// partials merged in LDS. da path uses bare exp2f on prescaled q/K/coords
// (identical values to expf). No-max softmax (logits bounded, fp32-exact):
// e = exp(logit) -> atomicAdd row sums -> AV over 128 ks -> atomicAdd OUT.
__global__ __launch_bounds__(256) void attn_kernel(
    const float* __restrict__ coord, float* __restrict__ ws)
{
  __shared__ __align__(16) float qjf[4 * CDIM];  // [j*4 + r]
  __shared__ __align__(16) float psc[2][4][128]; // [jh][r][k]
  __shared__ __align__(16) float posk[4][128];   // pos_aff (da only)
  __shared__ __align__(16) float se[4][128];     // exp(logit)
  __shared__ float red[2][4];
  __shared__ float qcr[4][3];
  __shared__ float wdl[3];
  int b = blockIdx.x, t = threadIdx.x;
  int br = (b < 1280) ? 1 : 0;        // da blocks dispatched first
  int bb = br ? b : b - 1280;
  int g = bb / 10, z = bb - g * 10;
  int n0 = g * 4, k0 = z * 128;

  const float* qsrc = ws + (br ? OFF_QDA : OFF_QSA);
  for (int i = t; i < 512; i += 256) {
    int r = i & 3, j = i >> 2;
    qjf[j * 4 + r] = qsrc[(n0 + r) * CDIM + j];
  }
  if (br) {
    if (t < 4) {
      int n = n0 + t;
      float x = (float)(n & 31), y = (float)(n >> 5);
      float u  = (x - 16.5f) * 0.19634954084936207f;  // pi/16
      float vv = (y -  8.5f) * 0.19634954084936207f;
      float cv = cosf(vv);
      qcr[t][0] = cv * sinf(u) * L2E;
      qcr[t][1] = sinf(vv) * L2E;
      qcr[t][2] = cv * cosf(u) * L2E;
    }
    if (t >= 64 && t < 67) wdl[t - 64] = ws[OFF_WDSUM + t - 64];
  }
  __syncthreads();

  int kl = t & 127, jh = t >> 7;
  int k = k0 + kl;
  {  // partial scores over this thread's 64-j half
    const float* kp = ws + (br ? OFF_KDAT : OFF_KSAT) + k + jh * 64 * NKV;
    const float4* qj = (const float4*)&qjf[jh * 64 * 4];
    float a0 = 0.f, a1 = 0.f, a2 = 0.f, a3 = 0.f;
    if (br) {
      #pragma unroll 4
      for (int j = 0; j < 64; ++j) {
        float kv = kp[j * NKV];
        float4 q = qj[j];
        a0 += exp2f(-fabsf(q.x - kv)); a1 += exp2f(-fabsf(q.y - kv));
        a2 += exp2f(-fabsf(q.z - kv)); a3 += exp2f(-fabsf(q.w - kv));
      }
    } else {
      #pragma unroll 8
      for (int j = 0; j < 64; ++j) {
        float kv = kp[j * NKV];
        float4 q = qj[j];
        a0 = fmaf(q.x, kv, a0); a1 = fmaf(q.y, kv, a1);
        a2 = fmaf(q.z, kv, a2); a3 = fmaf(q.w, kv, a3);
      }
    }
    psc[jh][0][kl] = a0; psc[jh][1][kl] = a1;
    psc[jh][2][kl] = a2; psc[jh][3][kl] = a3;
    if (br && jh == 1) {   // pos_aff for k, all 4 rows (prescaled coords)
      float c0 = coord[k * 3] * L2E;
      float c1 = coord[k * 3 + 1] * L2E;
      float c2 = coord[k * 3 + 2] * L2E;
      float w0 = wdl[0], w1 = wdl[1], w2 = wdl[2];
      #pragma unroll
      for (int r = 0; r < 4; ++r)
        posk[r][kl] = w0 * exp2f(-fabsf(qcr[r][0] - c0))
                    + w1 * exp2f(-fabsf(qcr[r][1] - c1))
                    + w2 * exp2f(-fabsf(qcr[r][2] - c2));
    }
  }
  __syncthreads();

  if (t < 128) {  // merge partials, exp2, reduce sums (waves 0-1)
    const float csa = 0.088388347648318447f * L2E;  // 128^-0.5 * log2e
    const float cda = 0.0078125f * L2E;             // (1/C) * log2e
    float s[4];
    #pragma unroll
    for (int r = 0; r < 4; ++r) {
      float tot = psc[0][r][t] + psc[1][r][t];
      float l = br ? (tot + posk[r][t]) * cda : tot * csa;
      float e = exp2f(l);
      se[r][t] = e;
      s[r] = e;
    }
    #pragma unroll
    for (int o = 32; o > 0; o >>= 1) {
      s[0] += __shfl_down(s[0], o, 64); s[1] += __shfl_down(s[1], o, 64);
      s[2] += __shfl_down(s[2], o, 64); s[3] += __shfl_down(s[3], o, 64);
    }
    if ((t & 63) == 0) {
      int w = t >> 6;
      red[w][0] = s[0]; red[w][1] = s[1]; red[w][2] = s[2]; red[w][3] = s[3];
    }
  }
  __syncthreads();   // covers se[] and red[]
  if (t < 4)
    atomicAdd(ws + OFF_SUMS + br * 512 + n0 + t, red[0][t] + red[1][t]);

  // AV: thread (c=t&127, h=t>>7) -> rows h, h+2 over all 128 ks
  int c = t & 127, h = t >> 7;
  const float* vp = ws + (br ? OFF_VDA : OFF_VSA) + k0 * CDIM + c;
  float acc0 = 0.f, acc1 = 0.f;
  #pragma unroll 4
  for (int ko = 0; ko < 128; ko += 4) {
    float4 pa = *(const float4*)&se[h][ko];
    float4 pb = *(const float4*)&se[h + 2][ko];
    float v0 = vp[(ko + 0) * CDIM];
    float v1 = vp[(ko + 1) * CDIM];
    float v2 = vp[(ko + 2) * CDIM];
    float v3 = vp[(ko + 3) * CDIM];
    acc0 = fmaf(pa.x, v0, acc0); acc1 = fmaf(pb.x, v0, acc1);
    acc0 = fmaf(pa.y, v1, acc0); acc1 = fmaf(pb.y, v1, acc1);
    acc0 = fmaf(pa.z, v2, acc0); acc1 = fmaf(pb.z, v2, acc1);
    acc0 = fmaf(pa.w, v3, acc0); acc1 = fmaf(pb.w, v3, acc1);
  }
  float* op = ws + OFF_OUT + br * (NQ * CDIM);
  atomicAdd(op + (n0 + h) * CDIM + c,     acc0);
  atomicAdd(op + (n0 + h + 2) * CDIM + c, acc1);
}

// ---------------------------------------------------------------- finalize
// one block (256 thr) per 2 query rows: normalize (divide by sums) with the
// reference's transpose-reshape on sa, project both, gate, fuse, NCHW store.
__global__ __launch_bounds__(256) void finalize_kernel(
    const float* __restrict__ psa, const float* __restrict__ bsa,
    const float* __restrict__ pda, const float* __restrict__ bda,
    const float* __restrict__ gsa, const float* __restrict__ gda,
    float* __restrict__ out, float* __restrict__ ws)
{
  __shared__ float sain[2][CDIM];
  __shared__ float dain[2][CDIM];
  __shared__ float cat[2][2 * CDIM];
  __shared__ float gl[2][2][CDIM];
  int i0 = blockIdx.x * 2, t = threadIdx.x;
  int h = t >> 7, c = t & 127;
  #pragma unroll
  for (int rr = 0; rr < 2; ++rr) {
    int i = i0 + rr;
    if (h == 0) {
      // sa_in[i][c] = out_sa[(i%4)*128 + c][i/4] / sum_sa[(i%4)*128 + c]
      int row = (i & 3) * 128 + c;
      float s = ws[OFF_SUMS + row];
      sain[rr][c] = ws[OFF_OUT + row * CDIM + (i >> 2)] / s;
    } else {
      float s = ws[OFF_SUMS + 512 + i];
      dain[rr][c] = ws[OFF_OUT + NQ * CDIM + i * CDIM + c] / s;
    }
  }
  __syncthreads();
  {
    const float4* w4 = (const float4*)((h ? pda : psa) + c * CDIM);
    const float* in0 = h ? dain[0] : sain[0];
    const float* in1 = h ? dain[1] : sain[1];
    float a0 = 0, a1 = 0, b0 = 0, b1 = 0;
    #pragma unroll 8
    for (int j4 = 0; j4 < 32; ++j4) {
      float4 wv = w4[j4];
      float4 x0 = *(const float4*)&in0[j4 * 4];
      float4 x1 = *(const float4*)&in1[j4 * 4];
      a0 = fmaf(wv.x, x0.x, a0); a1 = fmaf(wv.y, x0.y, a1);
      a0 = fmaf(wv.z, x0.z, a0); a1 = fmaf(wv.w, x0.w, a1);
      b0 = fmaf(wv.x, x1.x, b0); b1 = fmaf(wv.y, x1.y, b1);
      b0 = fmaf(wv.z, x1.z, b0); b1 = fmaf(wv.w, x1.w, b1);
    }
    float bias = h ? bda[c] : bsa[c];
    cat[0][h * CDIM + c] = bias + a0 + a1;
    cat[1][h * CDIM + c] = bias + b0 + b1;
  }
  __syncthreads();
  {
    const float4* g4 = (const float4*)((h ? gda : gsa) + c * 2 * CDIM);
    float a0 = 0, a1 = 0, b0 = 0, b1 = 0;
    #pragma unroll 8
    for (int j4 = 0; j4 < 64; ++j4) {
      float4 gv = g4[j4];
      float4 c0 = *(const float4*)&cat[0][j4 * 4];
      float4 c1 = *(const float4*)&cat[1][j4 * 4];
      a0 = fmaf(gv.x, c0.x, a0); a1 = fmaf(gv.y, c0.y, a1);
      a0 = fmaf(gv.z, c0.z, a0); a1 = fmaf(gv.w, c0.w, a1);
      b0 = fmaf(gv.x, c1.x, b0); b1 = fmaf(gv.y, c1.y, b1);
      b0 = fmaf(gv.z, c1.z, b0); b1 = fmaf(gv.w, c1.w, b1);
    }
    gl[0][h][c] = 1.0f / (1.0f + __expf(-(a0 + a1)));
    gl[1][h][c] = 1.0f / (1.0f + __expf(-(b0 + b1)));
  }
  __syncthreads();
  {  // h selects row, c selects channel
    int i = i0 + h;
    out[c * NQ + i] = gl[h][0][c] * cat[h][c] + gl[h][1][c] * cat[h][CDIM + c];
  }
}

// ---------------------------------------------------------------- launch
extern "C" void kernel_launch(void* const* d_in, const int* in_sizes, int n_in,
                              void* d_out, int out_size, void* d_ws, size_t ws_size,
                              hipStream_t stream)
{
  (void)in_sizes; (void)n_in; (void)out_size; (void)ws_size;
  const float* erp       = (const float*)d_in[0];
  const float* ico       = (const float*)d_in[1];
  const float* coord     = (const float*)d_in[2];
  const float* wq_sa     = (const float*)d_in[3];
  const float* wkv_sa    = (const float*)d_in[4];
  const float* proj_sa_w = (const float*)d_in[5];
  const float* proj_sa_b = (const float*)d_in[6];
  const float* wq_da     = (const float*)d_in[7];
  const float* wkv_da    = (const float*)d_in[8];
  const float* wdelta    = (const float*)d_in[9];
  const float* proj_da_w = (const float*)d_in[10];
  const float* proj_da_b = (const float*)d_in[11];
  const float* gate_sa   = (const float*)d_in[12];
  const float* gate_da   = (const float*)d_in[13];
  float* out = (float*)d_out;
  float* ws  = (float*)d_ws;

  hipLaunchKernelGGL(prep_kernel, dim3(577), dim3(256), 0, stream,
                     erp, ico, wq_sa, wq_da, wkv_sa, wkv_da, wdelta, ws);
  hipLaunchKernelGGL(attn_kernel, dim3(2560), dim3(256), 0, stream,
                     coord, ws);
  hipLaunchKernelGGL(finalize_kernel, dim3(256), dim3(256), 0, stream,
                     proj_sa_w, proj_sa_b, proj_da_w, proj_da_b,
                     gate_sa, gate_da, out, ws);
}